// Round 1
// 92.875 us; speedup vs baseline: 1.0304x; 1.0304x over previous
//
#include <hip/hip_runtime.h>

// bf16 MFMA implicit GEMM for 3x3 valid conv + bias — workspace-free edition.
// x: [32,64,64,64] f32, w: [64,64,3,3] f32, b: [64] f32, out: [32,64,62,62] f32
//
// Change vs previous round: the wprep pass + global workspace are gone. The
// f32->bf16 weight transform is folded into conv_mfma: each chunk's raw w
// segment (36 KB, L2-resident after first touch) is prefetched into registers
// during the MFMA loop (same pipeline slot as the x gather, so its latency
// hides), then packed into the SAME wl4 LDS layout in the pack phase.
// MFMA loop / x path / accumulation order are untouched -> bit-identical out.
//
// Per tap (r,s), per c-chunk of 16:  D[f][ow] += W[f][c] * X[c][ow]
// MFMA 32x32x16 bf16, A = w (m=f), B = x (n=ow)  ->  C/D col = lane&31 = ow.
// Block = 256 thr = 4 waves = (n, oh0..oh0+3); wave tile 64f x 64ow (2x2 MFMAs).

#define N_  32
#define OH_ 62
#define OW_ 62

typedef __attribute__((ext_vector_type(8)))  short short8;
typedef __attribute__((ext_vector_type(16))) float float16;

__device__ __forceinline__ unsigned short f2bf(float v) {
    unsigned int u = __builtin_bit_cast(unsigned int, v);
    u += 0x7FFFu + ((u >> 16) & 1u);
    return (unsigned short)(u >> 16);
}
__device__ __forceinline__ unsigned int pack2(float a, float b) {
    return (unsigned int)f2bf(a) | ((unsigned int)f2bf(b) << 16);
}
__device__ __forceinline__ short8 bc(uint4 v) {
    return __builtin_bit_cast(short8, v);
}

__global__ __launch_bounds__(256, 2) void conv_mfma(
    const float* __restrict__ x,
    const float* __restrict__ w,    // raw [64][64][3][3] f32
    const float* __restrict__ b,
    float* __restrict__ out)
{
    // x: [row6][col66][half2] uint4 units, col-stride 3 u4 (48 B, conflict-free)
    __shared__ uint4 xl4[6 * 66 * 3];            // 19008 B
    // w: [tap9][f64][half2] uint4 units, f-stride 3 u4 (48 B)
    __shared__ uint4 wl4[9 * 64 * 3];            // 27648 B

    const int n    = blockIdx.x;
    const int oh0  = blockIdx.y * 4;
    const int t    = threadIdx.x;
    const int wv   = t >> 6;          // wave id = oh offset
    const int ln31 = t & 31;
    const int cgrp = (t >> 5) & 1;    // k-half of the wave
    const int oh   = oh0 + wv;

    const float* xnb = x + (size_t)n * 64 * 4096;

    // w-prefetch coords: thread t owns f = t>>2, c-quarter q = t&3.
    // Per chunk it loads the 36 contiguous floats w[f][chunk*16+q*4 .. +4][0..9]
    // (36 B * 4 = 144 B, 16B-aligned) as 9 float4.
    const int wf    = t >> 2;
    const int wq    = t & 3;
    const int whalf = wq >> 1;        // c-half of the 16-chunk
    const float* wseg = w + wf * 576 + wq * 36;   // + chunk*144 per chunk

    float16 acc00 = {0}, acc01 = {0}, acc10 = {0}, acc11 = {0};

    // per-thread x gather coordinates: 3 (row, c-half) slices, 64-lane col runs
    int colv[3], halfv[3], rowv[3], rowg[3];
#pragma unroll
    for (int i = 0; i < 3; ++i) {
        int id = t + 256 * i;         // 0..767
        colv[i]  = id & 63;
        int rh   = id >> 6;           // 0..11
        halfv[i] = rh & 1;
        rowv[i]  = rh >> 1;           // 0..5
        int rg = oh0 + rowv[i]; if (rg > 63) rg = 63;
        rowg[i] = rg;
    }

    float g[3][8];        // x gather regs
    float wrf[36];        // w gather regs (all indices compile-time after unroll)

    // ---- gather chunk 0 (exposed once) ----
#pragma unroll
    for (int i = 0; i < 3; ++i) {
        const float* xp = xnb + (size_t)(halfv[i] * 8) * 4096 + rowg[i] * 64 + colv[i];
#pragma unroll
        for (int j = 0; j < 8; ++j) g[i][j] = xp[(size_t)j * 4096];
    }
    {
        const float4* ws4 = (const float4*)wseg;
#pragma unroll
        for (int j = 0; j < 9; ++j) {
            float4 v = ws4[j];
            wrf[4*j+0] = v.x; wrf[4*j+1] = v.y; wrf[4*j+2] = v.z; wrf[4*j+3] = v.w;
        }
    }

    for (int chunk = 0; chunk < 4; ++chunk) {
        __syncthreads();   // previous chunk's LDS readers done

        // ---- pack current x gather regs -> LDS (b128 writes) ----
#pragma unroll
        for (int i = 0; i < 3; ++i) {
            uint4 pv = { pack2(g[i][0], g[i][1]), pack2(g[i][2], g[i][3]),
                         pack2(g[i][4], g[i][5]), pack2(g[i][6], g[i][7]) };
            xl4[(rowv[i] * 66 + colv[i]) * 3 + halfv[i]] = pv;
        }

        // ---- pack current w regs -> LDS (b64 writes, same wl4 layout) ----
        // wrf index = cc*9 + tap, cc = 0..3 local channels of this quarter.
        // Slot (tap*64+f)*3+half holds channels half*8..+8; this thread fills
        // the (wq&1) 8-byte half of it: channels whalf*8 + (wq&1)*4 + {0..3}.
        {
            unsigned long long* wl8 = (unsigned long long*)wl4;
#pragma unroll
            for (int tap = 0; tap < 9; ++tap) {
                unsigned int lo = pack2(wrf[tap],      wrf[9  + tap]);
                unsigned int hi = pack2(wrf[18 + tap], wrf[27 + tap]);
                unsigned long long v =
                    (unsigned long long)lo | ((unsigned long long)hi << 32);
                wl8[((tap * 64 + wf) * 3 + whalf) * 2 + (wq & 1)] = v;
            }
        }
        __syncthreads();

        // ---- issue next chunk's gathers NOW; they drain during the MFMA loop ----
        if (chunk < 3) {
            const int c0n = (chunk + 1) * 16;
#pragma unroll
            for (int i = 0; i < 3; ++i) {
                const float* xp = xnb + (size_t)(c0n + halfv[i] * 8) * 4096
                                      + rowg[i] * 64 + colv[i];
#pragma unroll
                for (int j = 0; j < 8; ++j) g[i][j] = xp[(size_t)j * 4096];
            }
            const float4* ws4 = (const float4*)(wseg + (chunk + 1) * 144);
#pragma unroll
            for (int j = 0; j < 9; ++j) {
                float4 v = ws4[j];
                wrf[4*j+0] = v.x; wrf[4*j+1] = v.y; wrf[4*j+2] = v.z; wrf[4*j+3] = v.w;
            }
        }

        // ---- 9 taps x 2x2 MFMA, frags via ds_read_b128 (no vmcnt ops here) ----
#pragma unroll
        for (int r = 0; r < 3; ++r) {
            const int xrow = wv + r;
#pragma unroll
            for (int s = 0; s < 3; ++s) {
                const int tap = r * 3 + s;
                short8 a0 = bc(wl4[(tap * 64 + ln31)      * 3 + cgrp]);
                short8 a1 = bc(wl4[(tap * 64 + ln31 + 32) * 3 + cgrp]);
                short8 b0 = bc(xl4[(xrow * 66 + s + ln31)      * 3 + cgrp]);
                short8 b1 = bc(xl4[(xrow * 66 + s + ln31 + 32) * 3 + cgrp]);
                acc00 = __builtin_amdgcn_mfma_f32_32x32x16_bf16(a0, b0, acc00, 0, 0, 0);
                acc01 = __builtin_amdgcn_mfma_f32_32x32x16_bf16(a0, b1, acc01, 0, 0, 0);
                acc10 = __builtin_amdgcn_mfma_f32_32x32x16_bf16(a1, b0, acc10, 0, 0, 0);
                acc11 = __builtin_amdgcn_mfma_f32_32x32x16_bf16(a1, b1, acc11, 0, 0, 0);
            }
        }
    }

    // ---- epilogue: C/D row = (reg&3)+8*(reg>>2)+4*(lane>>5), col = lane&31 = ow ----
    if (oh < OH_) {
#pragma unroll
        for (int r = 0; r < 16; ++r) {
            int fr = (r & 3) + 8 * (r >> 2) + 4 * cgrp;
            float b0v = b[fr];
            float b1v = b[fr + 32];
            float* o0 = out + (((size_t)n * 64 + fr)      * OH_ + oh) * OW_;
            float* o1 = out + (((size_t)n * 64 + fr + 32) * OH_ + oh) * OW_;
            o0[ln31] = acc00[r] + b0v;
            o1[ln31] = acc10[r] + b1v;
            if (ln31 < 30) {
                o0[32 + ln31] = acc01[r] + b0v;
                o1[32 + ln31] = acc11[r] + b1v;
            }
        }
    }
}

extern "C" void kernel_launch(void* const* d_in, const int* in_sizes, int n_in,
                              void* d_out, int out_size, void* d_ws, size_t ws_size,
                              hipStream_t stream)
{
    const float* x = (const float*)d_in[0];
    const float* w = (const float*)d_in[1];
    const float* b = (const float*)d_in[2];
    float* out = (float*)d_out;
    (void)d_ws; (void)ws_size;        // workspace intentionally unused

    dim3 grid(N_, 16);                // 32 images x 16 oh-blocks
    conv_mfma<<<grid, 256, 0, stream>>>(x, w, b, out);
}